// Round 1
// baseline (1998.334 us; speedup 1.0000x reference)
//
#include <hip/hip_runtime.h>
#include <cstddef>
#include <cstdint>

#define N_NODES 12288
#define IN_CH   512
#define HID_CH  256
#define OUT_CH  8
#define E_EDGES 196608
#define TOT_EDGES (E_EDGES + N_NODES)

// ---------------------------------------------------------------- K0: init
__global__ void k_init(const float* __restrict__ logit_p,
                       const float* __restrict__ emb_w,
                       float* __restrict__ scale,
                       float* __restrict__ s1, float* __restrict__ s2,
                       float* __restrict__ lossacc,
                       int* __restrict__ deg, int* __restrict__ cursor) {
  int i = blockIdx.x * 256 + threadIdx.x;
  if (i < IN_CH) {
    const float EPSf = 2.220446049250313e-16f;
    float p = 1.f / (1.f + expf(-logit_p[i]));
    // log(0.5+EPS)-log(0.5+EPS) cancels exactly
    float approx = logf(p + EPSf) - logf(1.f - p + EPSf);
    float keep = 1.f - 1.f / (1.f + expf(-approx / 0.1f));
    float ew = 1.f / (1.f + expf(-emb_w[i]));
    scale[i] = keep * ew;
  }
  if (i < N_NODES) { s1[i] = 0.f; s2[i] = 0.f; deg[i] = 1; cursor[i] = 0; }
  if (i < 4) lossacc[i] = 0.f;
}

// ------------------------------------------------- K1: rowsum -> 1/(rs+1e-6)
__global__ __launch_bounds__(256) void k_rowsum(const float* __restrict__ x,
                                                const float* __restrict__ scale,
                                                float* __restrict__ rinv) {
  int wave = threadIdx.x >> 6, lane = threadIdx.x & 63;
  int node = blockIdx.x * 4 + wave;
  const float* xr = x + (size_t)node * IN_CH;
  float s = 0.f;
  for (int k = lane; k < IN_CH; k += 64) s += xr[k] * scale[k];
  #pragma unroll
  for (int off = 32; off > 0; off >>= 1) s += __shfl_down(s, off);
  if (lane == 0) rinv[node] = 1.f / (s + 1e-6f);
}

// ---------------------------------------------------- K2: xp1 = x @ W1 (raw x)
__global__ __launch_bounds__(256) void k_xp1(const float* __restrict__ x,
                                             const float* __restrict__ W1,
                                             float* __restrict__ xp1) {
  __shared__ float As[16][132];
  __shared__ float Bs[16][132];
  int t = threadIdx.x;
  int I = blockIdx.y * 128, J = blockIdx.x * 128;
  int tx = t & 15, ty = t >> 4;
  int i0 = ty * 8, j0 = tx * 8;
  int q = t & 3, rr = t >> 2;
  int bk = t >> 4, bc = t & 15;
  float acc[8][8] = {};
  for (int k0 = 0; k0 < IN_CH; k0 += 16) {
    int kq = k0 + 4 * q;
    float4 a0 = *(const float4*)&x[(size_t)(I + rr)      * IN_CH + kq];
    float4 a1 = *(const float4*)&x[(size_t)(I + rr + 64) * IN_CH + kq];
    float4 w0 = *(const float4*)&W1[(size_t)(k0 + bk) * HID_CH + J + 4 * bc];
    float4 w1 = *(const float4*)&W1[(size_t)(k0 + bk) * HID_CH + J + 64 + 4 * bc];
    __syncthreads();
    As[4*q+0][rr]    = a0.x; As[4*q+1][rr]    = a0.y;
    As[4*q+2][rr]    = a0.z; As[4*q+3][rr]    = a0.w;
    As[4*q+0][rr+64] = a1.x; As[4*q+1][rr+64] = a1.y;
    As[4*q+2][rr+64] = a1.z; As[4*q+3][rr+64] = a1.w;
    *(float4*)&Bs[bk][4*bc]      = w0;
    *(float4*)&Bs[bk][64+4*bc]   = w1;
    __syncthreads();
    #pragma unroll
    for (int kk = 0; kk < 16; kk++) {
      float4 av0 = *(const float4*)&As[kk][i0];
      float4 av1 = *(const float4*)&As[kk][i0+4];
      float4 bv0 = *(const float4*)&Bs[kk][j0];
      float4 bv1 = *(const float4*)&Bs[kk][j0+4];
      float av[8] = {av0.x,av0.y,av0.z,av0.w,av1.x,av1.y,av1.z,av1.w};
      float bv[8] = {bv0.x,bv0.y,bv0.z,bv0.w,bv1.x,bv1.y,bv1.z,bv1.w};
      #pragma unroll
      for (int r = 0; r < 8; r++)
        #pragma unroll
        for (int c = 0; c < 8; c++)
          acc[r][c] = fmaf(av[r], bv[c], acc[r][c]);
    }
  }
  #pragma unroll
  for (int r = 0; r < 8; r++) {
    float* op = xp1 + (size_t)(I + i0 + r) * HID_CH + J + j0;
    #pragma unroll
    for (int c = 0; c < 8; c++) op[c] = acc[r][c];
  }
}

// ------------------------------------------- K3: alpha_s1/alpha_d1 per node
__global__ __launch_bounds__(256) void k_alphas1(const float* __restrict__ xp1,
                                                 const float* __restrict__ a_src,
                                                 const float* __restrict__ a_dst,
                                                 float* __restrict__ as1,
                                                 float* __restrict__ ad1) {
  int wave = threadIdx.x >> 6, lane = threadIdx.x & 63;
  int node = blockIdx.x * 4 + wave;
  const float* r = xp1 + (size_t)node * HID_CH;
  float s = 0.f, d = 0.f;
  for (int k = lane; k < HID_CH; k += 64) { float v = r[k]; s += v * a_src[k]; d += v * a_dst[k]; }
  #pragma unroll
  for (int off = 32; off > 0; off >>= 1) { s += __shfl_down(s, off); d += __shfl_down(d, off); }
  if (lane == 0) { as1[node] = s; ad1[node] = d; }
}

// ---------------------------------------------------------- K4: degree count
__global__ void k_degree(const int* __restrict__ ei, int* __restrict__ deg) {
  int e = blockIdx.x * 256 + threadIdx.x;
  if (e < E_EDGES) atomicAdd(&deg[ei[E_EDGES + e]], 1);
}

// ----------------------------------------------------- K5: offsets (scan)
__global__ void k_scan(const int* __restrict__ deg, int* __restrict__ off) {
  __shared__ int buf[256];
  __shared__ int base_s;
  int t = threadIdx.x;
  if (t == 0) { base_s = 0; off[0] = 0; }
  __syncthreads();
  for (int c0 = 0; c0 < N_NODES; c0 += 256) {
    buf[t] = deg[c0 + t];
    __syncthreads();
    for (int s = 1; s < 256; s <<= 1) {
      int tv = (t >= s) ? buf[t - s] : 0;
      __syncthreads();
      buf[t] += tv;
      __syncthreads();
    }
    off[c0 + t + 1] = base_s + buf[t];
    __syncthreads();
    if (t == 0) base_s += buf[255];
    __syncthreads();
  }
}

// ----------------------------------------------------------- K6: CSR fill
__global__ void k_fill(const int* __restrict__ ei, const int* __restrict__ off,
                       int* __restrict__ cursor, int* __restrict__ csr) {
  int e = blockIdx.x * 256 + threadIdx.x;
  if (e < E_EDGES) {
    int s = ei[e], d = ei[E_EDGES + e];
    int pos = atomicAdd(&cursor[d], 1);
    csr[off[d] + pos] = s;
  } else if (e < TOT_EDGES) {
    int n2 = e - E_EDGES;
    int pos = atomicAdd(&cursor[n2], 1);
    csr[off[n2] + pos] = n2;
  }
}

// ----------------------- K7: GAT1 aggregation + bias + BN(eval) + leaky(0.01)
__global__ __launch_bounds__(256) void k_gat1(
    const float* __restrict__ xp1, const float* __restrict__ as1,
    const float* __restrict__ ad1, const int* __restrict__ off,
    const int* __restrict__ csr, const float* __restrict__ b1,
    const float* __restrict__ gamma, const float* __restrict__ beta,
    const float* __restrict__ mean, const float* __restrict__ var,
    float* __restrict__ hid) {
  __shared__ float w_s[256];
  __shared__ int   src_s[256];
  __shared__ float red[256];
  int n = blockIdx.x, t = threadIdx.x;
  int beg = off[n], deg = off[n + 1] - beg;
  float adn = ad1[n];
  float m = -1e30f;
  for (int k = t; k < deg; k += 256) {
    float e = as1[csr[beg + k]] + adn;
    e = e > 0.f ? e : 0.2f * e;
    m = fmaxf(m, e);
  }
  red[t] = m; __syncthreads();
  for (int s = 128; s > 0; s >>= 1) { if (t < s) red[t] = fmaxf(red[t], red[t + s]); __syncthreads(); }
  m = red[0];
  __syncthreads();
  float acc = 0.f, dsum = 0.f;
  for (int k0 = 0; k0 < deg; k0 += 256) {
    int kk = k0 + t;
    float w = 0.f; int s = 0;
    if (kk < deg) {
      s = csr[beg + kk];
      float e = as1[s] + adn;
      e = e > 0.f ? e : 0.2f * e;
      w = expf(e - m);
    }
    w_s[t] = w; src_s[t] = s;
    dsum += w;
    __syncthreads();
    int lim = min(256, deg - k0);
    for (int q = 0; q < lim; q++)
      acc = fmaf(w_s[q], xp1[(size_t)src_s[q] * HID_CH + t], acc);
    __syncthreads();
  }
  red[t] = dsum; __syncthreads();
  for (int s = 128; s > 0; s >>= 1) { if (t < s) red[t] += red[t + s]; __syncthreads(); }
  float denom = red[0];
  float v = acc / (denom + 1e-16f) + b1[t];
  v = (v - mean[t]) * rsqrtf(var[t] + 1e-5f) * gamma[t] + beta[t];
  v = v > 0.f ? v : 0.01f * v;
  hid[(size_t)n * HID_CH + t] = v;
}

// --------------------------------------------------- K8: xp2 = hid @ W2
__global__ void k_xp2(const float* __restrict__ hid, const float* __restrict__ W2,
                      float* __restrict__ xp2) {
  int idx = blockIdx.x * 256 + threadIdx.x;
  if (idx >= N_NODES * OUT_CH) return;
  int i = idx >> 3, c = idx & 7;
  const float* h = hid + (size_t)i * HID_CH;
  float s = 0.f;
  #pragma unroll 8
  for (int k = 0; k < HID_CH; k++) s = fmaf(h[k], W2[k * OUT_CH + c], s);
  xp2[idx] = s;
}

// ------------------------------------------- K9: alpha_s2/alpha_d2 per node
__global__ void k_alphas2(const float* __restrict__ xp2,
                          const float* __restrict__ a_src2,
                          const float* __restrict__ a_dst2,
                          float* __restrict__ as2, float* __restrict__ ad2) {
  int i = blockIdx.x * 256 + threadIdx.x;
  if (i >= N_NODES) return;
  const float* r = xp2 + (size_t)i * OUT_CH;
  float s = 0.f, d = 0.f;
  #pragma unroll
  for (int c = 0; c < OUT_CH; c++) { float v = r[c]; s += v * a_src2[c]; d += v * a_dst2[c]; }
  as2[i] = s; ad2[i] = d;
}

// --------------- K10: GAT2 aggregation + log_softmax + node_p + loss pieces
__global__ __launch_bounds__(64) void k_gat2(
    const float* __restrict__ xp2, const float* __restrict__ as2,
    const float* __restrict__ ad2, const int* __restrict__ off,
    const int* __restrict__ csr, const float* __restrict__ b2,
    const int* __restrict__ y, const int* __restrict__ mask,
    float* __restrict__ node_p, float* __restrict__ lossacc) {
  int n = blockIdx.x, l = threadIdx.x;
  int beg = off[n], deg = off[n + 1] - beg;
  float adn = ad2[n];
  float m = -1e30f;
  for (int k = l; k < deg; k += 64) {
    float e = as2[csr[beg + k]] + adn;
    e = e > 0.f ? e : 0.2f * e;
    m = fmaxf(m, e);
  }
  #pragma unroll
  for (int o = 32; o > 0; o >>= 1) m = fmaxf(m, __shfl_xor(m, o));
  int g = l >> 3, c = l & 7;
  float acc = 0.f, dsum = 0.f;
  for (int k0 = 0; k0 < deg; k0 += 8) {
    int kk = k0 + g;
    if (kk < deg) {
      int s = csr[beg + kk];
      float e = as2[s] + adn;
      e = e > 0.f ? e : 0.2f * e;
      float w = expf(e - m);
      acc = fmaf(w, xp2[(size_t)s * OUT_CH + c], acc);
      if (c == 0) dsum += w;
    }
  }
  #pragma unroll
  for (int o = 8; o < 64; o <<= 1) { acc += __shfl_xor(acc, o); dsum += __shfl_xor(dsum, o); }
  float denom = __shfl(dsum, 0);
  float v = acc / (denom + 1e-16f) + b2[c];
  float mx = v;
  #pragma unroll
  for (int o = 1; o < 8; o <<= 1) mx = fmaxf(mx, __shfl_xor(mx, o));
  float ex = expf(v - mx), ssum = ex;
  #pragma unroll
  for (int o = 1; o < 8; o <<= 1) ssum += __shfl_xor(ssum, o);
  float ls = v - mx - logf(ssum);
  if (l == 1) node_p[n] = expf(ls);
  int msk = mask[n];
  if (l == y[n] && msk) atomicAdd(&lossacc[0], ls);
  if (l == 0 && msk) atomicAdd(&lossacc[1], 1.f);
}

// ------- K11: SYMMETRIC graph tile GEMM. xe@xe^T is a Gram matrix: compute
// only upper-triangle 128x128 blocks (4656 of 9216 => 50.5% of FLOPs), write
// both the tile (scaled by rinv[col]) and its transpose (scaled by rinv[row]).
// s1/s2 row-accumulators fed for BOTH sides; transposed-side partials reduced
// through the (now free) As/Bs LDS buffers to keep global atomics low.
// NOTE: gout is only 4B-aligned (offset 2N+1 floats in d_out) -> scalar stores.
__global__ __launch_bounds__(256) void k_graph(
    const float* __restrict__ x, const float* __restrict__ scale,
    const float* __restrict__ rinv, const float* __restrict__ node_p,
    float* __restrict__ gout, float* __restrict__ s1, float* __restrict__ s2) {
  __shared__ float As[16][132];
  __shared__ float Bs[16][132];
  int t = threadIdx.x;
  // ---- decode upper-triangle block pair (by <= bx) from linear block index
  int kb = blockIdx.x;
  int by = (int)(0.5f * (193.0f - sqrtf(37249.0f - 8.0f * (float)kb)));
  by = by < 0 ? 0 : (by > 95 ? 95 : by);
  while ((by + 1) * 96 - (((by + 1) * by) >> 1) <= kb) by++;
  while (by * 96 - ((by * (by - 1)) >> 1) > kb) by--;
  int bx = by + (kb - (by * 96 - ((by * (by - 1)) >> 1)));
  int I = by * 128, J = bx * 128;
  bool diag = (by == bx);

  int tx = t & 15, ty = t >> 4;
  int i0 = ty * 8, j0 = tx * 8;
  int q = t & 3, rr = t >> 2;
  float acc[8][8] = {};
  for (int k0 = 0; k0 < IN_CH; k0 += 16) {
    int kq = k0 + 4 * q;
    float4 a0 = *(const float4*)&x[(size_t)(I + rr)      * IN_CH + kq];
    float4 a1 = *(const float4*)&x[(size_t)(I + rr + 64) * IN_CH + kq];
    float4 b0 = *(const float4*)&x[(size_t)(J + rr)      * IN_CH + kq];
    float4 b1 = *(const float4*)&x[(size_t)(J + rr + 64) * IN_CH + kq];
    float sc0 = scale[kq], sc1 = scale[kq + 1], sc2 = scale[kq + 2], sc3 = scale[kq + 3];
    __syncthreads();
    As[4*q+0][rr]    = a0.x*sc0; As[4*q+1][rr]    = a0.y*sc1;
    As[4*q+2][rr]    = a0.z*sc2; As[4*q+3][rr]    = a0.w*sc3;
    As[4*q+0][rr+64] = a1.x*sc0; As[4*q+1][rr+64] = a1.y*sc1;
    As[4*q+2][rr+64] = a1.z*sc2; As[4*q+3][rr+64] = a1.w*sc3;
    Bs[4*q+0][rr]    = b0.x*sc0; Bs[4*q+1][rr]    = b0.y*sc1;
    Bs[4*q+2][rr]    = b0.z*sc2; Bs[4*q+3][rr]    = b0.w*sc3;
    Bs[4*q+0][rr+64] = b1.x*sc0; Bs[4*q+1][rr+64] = b1.y*sc1;
    Bs[4*q+2][rr+64] = b1.z*sc2; Bs[4*q+3][rr+64] = b1.w*sc3;
    __syncthreads();
    #pragma unroll
    for (int kk = 0; kk < 16; kk++) {
      float4 av0 = *(const float4*)&As[kk][i0];
      float4 av1 = *(const float4*)&As[kk][i0+4];
      float4 bv0 = *(const float4*)&Bs[kk][j0];
      float4 bv1 = *(const float4*)&Bs[kk][j0+4];
      float av[8] = {av0.x,av0.y,av0.z,av0.w,av1.x,av1.y,av1.z,av1.w};
      float bv[8] = {bv0.x,bv0.y,bv0.z,bv0.w,bv1.x,bv1.y,bv1.z,bv1.w};
      #pragma unroll
      for (int r = 0; r < 8; r++)
        #pragma unroll
        for (int c = 0; c < 8; c++)
          acc[r][c] = fmaf(av[r], bv[c], acc[r][c]);
    }
  }

  // ---- normal side: rows I.., cols J..  (graph[i][j] = dot * rinv[j])
  int Jb = J + j0;
  float rj[8], pj[8];
  #pragma unroll
  for (int c = 0; c < 8; c++) { rj[c] = rinv[Jb + c]; pj[c] = node_p[Jb + c]; }
  float s1p[8], s2p[8];
  #pragma unroll
  for (int r = 0; r < 8; r++) {
    float* gp = gout + (size_t)(I + i0 + r) * N_NODES + Jb;
    float a1s = 0.f, a2s = 0.f;
    #pragma unroll
    for (int c = 0; c < 8; c++) {
      float gv = acc[r][c] * rj[c];
      gp[c] = gv;
      a1s += gv; a2s += gv * pj[c];
    }
    s1p[r] = a1s; s2p[r] = a2s;
  }
  #pragma unroll
  for (int r = 0; r < 8; r++) {
    #pragma unroll
    for (int off = 8; off > 0; off >>= 1) {
      s1p[r] += __shfl_down(s1p[r], off, 16);
      s2p[r] += __shfl_down(s2p[r], off, 16);
    }
  }
  if (tx == 0) {
    #pragma unroll
    for (int r = 0; r < 8; r++) {
      atomicAdd(&s1[I + i0 + r], s1p[r]);
      atomicAdd(&s2[I + i0 + r], s2p[r]);
    }
  }

  // ---- transposed side (off-diagonal only): rows J.., cols I..
  // graph[j][i] = dot * rinv[i]
  if (!diag) {
    float ri[8], pi[8];
    #pragma unroll
    for (int r = 0; r < 8; r++) { ri[r] = rinv[I + i0 + r]; pi[r] = node_p[I + i0 + r]; }
    float t1[8], t2[8];
    #pragma unroll
    for (int c = 0; c < 8; c++) {
      float* gp = gout + (size_t)(J + j0 + c) * N_NODES + I + i0;
      float ts1 = 0.f, ts2 = 0.f;
      #pragma unroll
      for (int r = 0; r < 8; r++) {
        float gv = acc[r][c] * ri[r];
        gp[r] = gv;
        ts1 += gv; ts2 += gv * pi[r];
      }
      t1[c] = ts1; t2[c] = ts2;
    }
    // reduce t1/t2 over the 16 ty-groups via LDS (As/Bs are dead now)
    __syncthreads();
    #pragma unroll
    for (int c = 0; c < 8; c++) { As[ty][j0 + c] = t1[c]; Bs[ty][j0 + c] = t2[c]; }
    __syncthreads();
    if (t < 128) {
      float v1 = 0.f, v2 = 0.f;
      #pragma unroll
      for (int w2 = 0; w2 < 16; w2++) { v1 += As[w2][t]; v2 += Bs[w2][t]; }
      atomicAdd(&s1[J + t], v1);
      atomicAdd(&s2[J + t], v2);
    }
  }
}

// ------------------------------------------------ K12: out1 softmax + loss
__global__ void k_final(const float* __restrict__ s1, const float* __restrict__ s2,
                        const float* __restrict__ lossacc, float* __restrict__ out) {
  int i = blockIdx.x * 256 + threadIdx.x;
  if (i < N_NODES) {
    float b = s2[i];          // adj_p
    float a = s1[i] - s2[i];  // adj_p_nag
    float m = fmaxf(a, b);
    float ea = expf(a - m), eb = expf(b - m);
    float inv = 1.f / (ea + eb);
    out[i * 2 + 0] = ea * inv;
    out[i * 2 + 1] = eb * inv;
  }
  if (i == 0) out[2 * N_NODES] = -lossacc[0] / lossacc[1];
}

// ============================================================= launch
extern "C" void kernel_launch(void* const* d_in, const int* in_sizes, int n_in,
                              void* d_out, int out_size, void* d_ws, size_t ws_size,
                              hipStream_t stream) {
  const float* x       = (const float*)d_in[0];
  const int*   ei      = (const int*)  d_in[1];
  const int*   y       = (const int*)  d_in[2];
  const int*   mask    = (const int*)  d_in[3];
  const float* W1      = (const float*)d_in[4];
  const float* a_src1  = (const float*)d_in[5];
  const float* a_dst1  = (const float*)d_in[6];
  const float* b1      = (const float*)d_in[7];
  const float* W2      = (const float*)d_in[8];
  const float* a_src2  = (const float*)d_in[9];
  const float* a_dst2  = (const float*)d_in[10];
  const float* b2      = (const float*)d_in[11];
  const float* gamma   = (const float*)d_in[12];
  const float* beta    = (const float*)d_in[13];
  const float* mean    = (const float*)d_in[14];
  const float* var     = (const float*)d_in[15];
  const float* emb_w   = (const float*)d_in[16];
  const float* logit_p = (const float*)d_in[17];

  float* out  = (float*)d_out;
  float* gout = out + 2 * N_NODES + 1;   // graph starts after out1 (N*2) + loss (1)

  char* w = (char*)d_ws;
  auto alloc = [&](size_t bytes) -> void* {
    void* p = (void*)w;
    w += (bytes + 255) & ~(size_t)255;
    return p;
  };
  float* xp1    = (float*)alloc((size_t)N_NODES * HID_CH * 4);
  float* hid    = (float*)alloc((size_t)N_NODES * HID_CH * 4);
  float* xp2    = (float*)alloc((size_t)N_NODES * OUT_CH * 4);
  float* as1    = (float*)alloc((size_t)N_NODES * 4);
  float* ad1    = (float*)alloc((size_t)N_NODES * 4);
  float* as2    = (float*)alloc((size_t)N_NODES * 4);
  float* ad2    = (float*)alloc((size_t)N_NODES * 4);
  float* rinv   = (float*)alloc((size_t)N_NODES * 4);
  float* node_p = (float*)alloc((size_t)N_NODES * 4);
  float* s1     = (float*)alloc((size_t)N_NODES * 4);
  float* s2     = (float*)alloc((size_t)N_NODES * 4);
  float* scale  = (float*)alloc((size_t)IN_CH * 4);
  float* lossacc= (float*)alloc(64);
  int*   deg    = (int*)  alloc((size_t)N_NODES * 4);
  int*   off    = (int*)  alloc((size_t)(N_NODES + 1) * 4);
  int*   cursor = (int*)  alloc((size_t)N_NODES * 4);
  int*   csr    = (int*)  alloc((size_t)TOT_EDGES * 4);

  k_init<<<N_NODES / 256, 256, 0, stream>>>(logit_p, emb_w, scale, s1, s2, lossacc, deg, cursor);
  k_rowsum<<<N_NODES / 4, 256, 0, stream>>>(x, scale, rinv);
  k_xp1<<<dim3(HID_CH / 128, N_NODES / 128), 256, 0, stream>>>(x, W1, xp1);
  k_alphas1<<<N_NODES / 4, 256, 0, stream>>>(xp1, a_src1, a_dst1, as1, ad1);
  k_degree<<<E_EDGES / 256, 256, 0, stream>>>(ei, deg);
  k_scan<<<1, 256, 0, stream>>>(deg, off);
  k_fill<<<(TOT_EDGES + 255) / 256, 256, 0, stream>>>(ei, off, cursor, csr);
  k_gat1<<<N_NODES, 256, 0, stream>>>(xp1, as1, ad1, off, csr, b1, gamma, beta, mean, var, hid);
  k_xp2<<<(N_NODES * OUT_CH) / 256, 256, 0, stream>>>(hid, W2, xp2);
  k_alphas2<<<N_NODES / 256, 256, 0, stream>>>(xp2, a_src2, a_dst2, as2, ad2);
  k_gat2<<<N_NODES, 64, 0, stream>>>(xp2, as2, ad2, off, csr, b2, y, mask, node_p, lossacc);
  // upper-triangle blocks only: 96*97/2 = 4656
  k_graph<<<4656, 256, 0, stream>>>(x, scale, rinv, node_p, gout, s1, s2);
  k_final<<<N_NODES / 256, 256, 0, stream>>>(s1, s2, lossacc, out);
}

// Round 2
// 1339.686 us; speedup vs baseline: 1.4916x; 1.4916x over previous
//
#include <hip/hip_runtime.h>
#include <cstddef>
#include <cstdint>

#define N_NODES 12288
#define IN_CH   512
#define HID_CH  256
#define OUT_CH  8
#define E_EDGES 196608
#define TOT_EDGES (E_EDGES + N_NODES)

typedef _Float16 f16x8 __attribute__((ext_vector_type(8)));
typedef float    f32x4 __attribute__((ext_vector_type(4)));

// ---------------------------------------------------------------- K0: init
__global__ void k_init(const float* __restrict__ logit_p,
                       const float* __restrict__ emb_w,
                       float* __restrict__ scale,
                       float* __restrict__ s1, float* __restrict__ s2,
                       float* __restrict__ lossacc,
                       int* __restrict__ deg, int* __restrict__ cursor) {
  int i = blockIdx.x * 256 + threadIdx.x;
  if (i < IN_CH) {
    const float EPSf = 2.220446049250313e-16f;
    float p = 1.f / (1.f + expf(-logit_p[i]));
    // log(0.5+EPS)-log(0.5+EPS) cancels exactly
    float approx = logf(p + EPSf) - logf(1.f - p + EPSf);
    float keep = 1.f - 1.f / (1.f + expf(-approx / 0.1f));
    float ew = 1.f / (1.f + expf(-emb_w[i]));
    scale[i] = keep * ew;
  }
  if (i < N_NODES) { s1[i] = 0.f; s2[i] = 0.f; deg[i] = 1; cursor[i] = 0; }
  if (i < 4) lossacc[i] = 0.f;
}

// ------------------------------------------------- K1: rowsum -> 1/(rs+1e-6)
__global__ __launch_bounds__(256) void k_rowsum(const float* __restrict__ x,
                                                const float* __restrict__ scale,
                                                float* __restrict__ rinv) {
  int wave = threadIdx.x >> 6, lane = threadIdx.x & 63;
  int node = blockIdx.x * 4 + wave;
  const float* xr = x + (size_t)node * IN_CH;
  float s = 0.f;
  for (int k = lane; k < IN_CH; k += 64) s += xr[k] * scale[k];
  #pragma unroll
  for (int off = 32; off > 0; off >>= 1) s += __shfl_down(s, off);
  if (lane == 0) rinv[node] = 1.f / (s + 1e-6f);
}

// ---------------- K1b: prep xe = x*scale as f16 hi/lo planes, PRE-SWIZZLED
// into MFMA 16x16x32 fragment order. Storage (f16 units):
//   addr = p*65536 + s*4096 + g*512 + kb*128 + rowin*8 + kin
// where row = p*128 + g*16 + rowin, k = s*32 + kb*8 + kin.
// A fragment read for (panel p, kstep s, group g) is then: lane L reads
// 8 halves at addr = base + L*8  (contiguous, coalesced, 16B aligned).
__global__ __launch_bounds__(256) void k_prep(const float* __restrict__ x,
                                              const float* __restrict__ scale,
                                              _Float16* __restrict__ xh,
                                              _Float16* __restrict__ xl) {
  int tid = blockIdx.x * 256 + threadIdx.x;   // 786432 total
  int rowin = tid & 15;
  int kb    = (tid >> 4) & 3;
  int g     = (tid >> 6) & 7;
  int s     = (tid >> 9) & 15;
  int p     = tid >> 13;
  int row = p * 128 + g * 16 + rowin;
  int k   = s * 32 + kb * 8;
  const float* xp = x + (size_t)row * IN_CH + k;
  f16x8 h, l;
  #pragma unroll
  for (int j = 0; j < 8; ++j) {
    float v = xp[j] * scale[k + j];
    _Float16 hv = (_Float16)v;            // RTN
    h[j] = hv;
    l[j] = (_Float16)(v - (float)hv);     // residual, ~2^-22 rel error total
  }
  *(f16x8*)(xh + (size_t)tid * 8) = h;
  *(f16x8*)(xl + (size_t)tid * 8) = l;
}

// ---------------------------------------------------- K2: xp1 = x @ W1 (raw x)
__global__ __launch_bounds__(256) void k_xp1(const float* __restrict__ x,
                                             const float* __restrict__ W1,
                                             float* __restrict__ xp1) {
  __shared__ float As[16][132];
  __shared__ float Bs[16][132];
  int t = threadIdx.x;
  int I = blockIdx.y * 128, J = blockIdx.x * 128;
  int tx = t & 15, ty = t >> 4;
  int i0 = ty * 8, j0 = tx * 8;
  int q = t & 3, rr = t >> 2;
  int bk = t >> 4, bc = t & 15;
  float acc[8][8] = {};
  for (int k0 = 0; k0 < IN_CH; k0 += 16) {
    int kq = k0 + 4 * q;
    float4 a0 = *(const float4*)&x[(size_t)(I + rr)      * IN_CH + kq];
    float4 a1 = *(const float4*)&x[(size_t)(I + rr + 64) * IN_CH + kq];
    float4 w0 = *(const float4*)&W1[(size_t)(k0 + bk) * HID_CH + J + 4 * bc];
    float4 w1 = *(const float4*)&W1[(size_t)(k0 + bk) * HID_CH + J + 64 + 4 * bc];
    __syncthreads();
    As[4*q+0][rr]    = a0.x; As[4*q+1][rr]    = a0.y;
    As[4*q+2][rr]    = a0.z; As[4*q+3][rr]    = a0.w;
    As[4*q+0][rr+64] = a1.x; As[4*q+1][rr+64] = a1.y;
    As[4*q+2][rr+64] = a1.z; As[4*q+3][rr+64] = a1.w;
    *(float4*)&Bs[bk][4*bc]      = w0;
    *(float4*)&Bs[bk][64+4*bc]   = w1;
    __syncthreads();
    #pragma unroll
    for (int kk = 0; kk < 16; kk++) {
      float4 av0 = *(const float4*)&As[kk][i0];
      float4 av1 = *(const float4*)&As[kk][i0+4];
      float4 bv0 = *(const float4*)&Bs[kk][j0];
      float4 bv1 = *(const float4*)&Bs[kk][j0+4];
      float av[8] = {av0.x,av0.y,av0.z,av0.w,av1.x,av1.y,av1.z,av1.w};
      float bv[8] = {bv0.x,bv0.y,bv0.z,bv0.w,bv1.x,bv1.y,bv1.z,bv1.w};
      #pragma unroll
      for (int r = 0; r < 8; r++)
        #pragma unroll
        for (int c = 0; c < 8; c++)
          acc[r][c] = fmaf(av[r], bv[c], acc[r][c]);
    }
  }
  #pragma unroll
  for (int r = 0; r < 8; r++) {
    float* op = xp1 + (size_t)(I + i0 + r) * HID_CH + J + j0;
    #pragma unroll
    for (int c = 0; c < 8; c++) op[c] = acc[r][c];
  }
}

// ------------------------------------------- K3: alpha_s1/alpha_d1 per node
__global__ __launch_bounds__(256) void k_alphas1(const float* __restrict__ xp1,
                                                 const float* __restrict__ a_src,
                                                 const float* __restrict__ a_dst,
                                                 float* __restrict__ as1,
                                                 float* __restrict__ ad1) {
  int wave = threadIdx.x >> 6, lane = threadIdx.x & 63;
  int node = blockIdx.x * 4 + wave;
  const float* r = xp1 + (size_t)node * HID_CH;
  float s = 0.f, d = 0.f;
  for (int k = lane; k < HID_CH; k += 64) { float v = r[k]; s += v * a_src[k]; d += v * a_dst[k]; }
  #pragma unroll
  for (int off = 32; off > 0; off >>= 1) { s += __shfl_down(s, off); d += __shfl_down(d, off); }
  if (lane == 0) { as1[node] = s; ad1[node] = d; }
}

// ---------------------------------------------------------- K4: degree count
__global__ void k_degree(const int* __restrict__ ei, int* __restrict__ deg) {
  int e = blockIdx.x * 256 + threadIdx.x;
  if (e < E_EDGES) atomicAdd(&deg[ei[E_EDGES + e]], 1);
}

// ----------------------------------------------------- K5: offsets (scan)
__global__ void k_scan(const int* __restrict__ deg, int* __restrict__ off) {
  __shared__ int buf[256];
  __shared__ int base_s;
  int t = threadIdx.x;
  if (t == 0) { base_s = 0; off[0] = 0; }
  __syncthreads();
  for (int c0 = 0; c0 < N_NODES; c0 += 256) {
    buf[t] = deg[c0 + t];
    __syncthreads();
    for (int s = 1; s < 256; s <<= 1) {
      int tv = (t >= s) ? buf[t - s] : 0;
      __syncthreads();
      buf[t] += tv;
      __syncthreads();
    }
    off[c0 + t + 1] = base_s + buf[t];
    __syncthreads();
    if (t == 0) base_s += buf[255];
    __syncthreads();
  }
}

// ----------------------------------------------------------- K6: CSR fill
__global__ void k_fill(const int* __restrict__ ei, const int* __restrict__ off,
                       int* __restrict__ cursor, int* __restrict__ csr) {
  int e = blockIdx.x * 256 + threadIdx.x;
  if (e < E_EDGES) {
    int s = ei[e], d = ei[E_EDGES + e];
    int pos = atomicAdd(&cursor[d], 1);
    csr[off[d] + pos] = s;
  } else if (e < TOT_EDGES) {
    int n2 = e - E_EDGES;
    int pos = atomicAdd(&cursor[n2], 1);
    csr[off[n2] + pos] = n2;
  }
}

// ----------------------- K7: GAT1 aggregation + bias + BN(eval) + leaky(0.01)
__global__ __launch_bounds__(256) void k_gat1(
    const float* __restrict__ xp1, const float* __restrict__ as1,
    const float* __restrict__ ad1, const int* __restrict__ off,
    const int* __restrict__ csr, const float* __restrict__ b1,
    const float* __restrict__ gamma, const float* __restrict__ beta,
    const float* __restrict__ mean, const float* __restrict__ var,
    float* __restrict__ hid) {
  __shared__ float w_s[256];
  __shared__ int   src_s[256];
  __shared__ float red[256];
  int n = blockIdx.x, t = threadIdx.x;
  int beg = off[n], deg = off[n + 1] - beg;
  float adn = ad1[n];
  float m = -1e30f;
  for (int k = t; k < deg; k += 256) {
    float e = as1[csr[beg + k]] + adn;
    e = e > 0.f ? e : 0.2f * e;
    m = fmaxf(m, e);
  }
  red[t] = m; __syncthreads();
  for (int s = 128; s > 0; s >>= 1) { if (t < s) red[t] = fmaxf(red[t], red[t + s]); __syncthreads(); }
  m = red[0];
  __syncthreads();
  float acc = 0.f, dsum = 0.f;
  for (int k0 = 0; k0 < deg; k0 += 256) {
    int kk = k0 + t;
    float w = 0.f; int s = 0;
    if (kk < deg) {
      s = csr[beg + kk];
      float e = as1[s] + adn;
      e = e > 0.f ? e : 0.2f * e;
      w = expf(e - m);
    }
    w_s[t] = w; src_s[t] = s;
    dsum += w;
    __syncthreads();
    int lim = min(256, deg - k0);
    for (int q = 0; q < lim; q++)
      acc = fmaf(w_s[q], xp1[(size_t)src_s[q] * HID_CH + t], acc);
    __syncthreads();
  }
  red[t] = dsum; __syncthreads();
  for (int s = 128; s > 0; s >>= 1) { if (t < s) red[t] += red[t + s]; __syncthreads(); }
  float denom = red[0];
  float v = acc / (denom + 1e-16f) + b1[t];
  v = (v - mean[t]) * rsqrtf(var[t] + 1e-5f) * gamma[t] + beta[t];
  v = v > 0.f ? v : 0.01f * v;
  hid[(size_t)n * HID_CH + t] = v;
}

// --------------------------------------------------- K8: xp2 = hid @ W2
__global__ void k_xp2(const float* __restrict__ hid, const float* __restrict__ W2,
                      float* __restrict__ xp2) {
  int idx = blockIdx.x * 256 + threadIdx.x;
  if (idx >= N_NODES * OUT_CH) return;
  int i = idx >> 3, c = idx & 7;
  const float* h = hid + (size_t)i * HID_CH;
  float s = 0.f;
  #pragma unroll 8
  for (int k = 0; k < HID_CH; k++) s = fmaf(h[k], W2[k * OUT_CH + c], s);
  xp2[idx] = s;
}

// ------------------------------------------- K9: alpha_s2/alpha_d2 per node
__global__ void k_alphas2(const float* __restrict__ xp2,
                          const float* __restrict__ a_src2,
                          const float* __restrict__ a_dst2,
                          float* __restrict__ as2, float* __restrict__ ad2) {
  int i = blockIdx.x * 256 + threadIdx.x;
  if (i >= N_NODES) return;
  const float* r = xp2 + (size_t)i * OUT_CH;
  float s = 0.f, d = 0.f;
  #pragma unroll
  for (int c = 0; c < OUT_CH; c++) { float v = r[c]; s += v * a_src2[c]; d += v * a_dst2[c]; }
  as2[i] = s; ad2[i] = d;
}

// --------------- K10: GAT2 aggregation + log_softmax + node_p + loss pieces
__global__ __launch_bounds__(64) void k_gat2(
    const float* __restrict__ xp2, const float* __restrict__ as2,
    const float* __restrict__ ad2, const int* __restrict__ off,
    const int* __restrict__ csr, const float* __restrict__ b2,
    const int* __restrict__ y, const int* __restrict__ mask,
    float* __restrict__ node_p, float* __restrict__ lossacc) {
  int n = blockIdx.x, l = threadIdx.x;
  int beg = off[n], deg = off[n + 1] - beg;
  float adn = ad2[n];
  float m = -1e30f;
  for (int k = l; k < deg; k += 64) {
    float e = as2[csr[beg + k]] + adn;
    e = e > 0.f ? e : 0.2f * e;
    m = fmaxf(m, e);
  }
  #pragma unroll
  for (int o = 32; o > 0; o >>= 1) m = fmaxf(m, __shfl_xor(m, o));
  int g = l >> 3, c = l & 7;
  float acc = 0.f, dsum = 0.f;
  for (int k0 = 0; k0 < deg; k0 += 8) {
    int kk = k0 + g;
    if (kk < deg) {
      int s = csr[beg + kk];
      float e = as2[s] + adn;
      e = e > 0.f ? e : 0.2f * e;
      float w = expf(e - m);
      acc = fmaf(w, xp2[(size_t)s * OUT_CH + c], acc);
      if (c == 0) dsum += w;
    }
  }
  #pragma unroll
  for (int o = 8; o < 64; o <<= 1) { acc += __shfl_xor(acc, o); dsum += __shfl_xor(dsum, o); }
  float denom = __shfl(dsum, 0);
  float v = acc / (denom + 1e-16f) + b2[c];
  float mx = v;
  #pragma unroll
  for (int o = 1; o < 8; o <<= 1) mx = fmaxf(mx, __shfl_xor(mx, o));
  float ex = expf(v - mx), ssum = ex;
  #pragma unroll
  for (int o = 1; o < 8; o <<= 1) ssum += __shfl_xor(ssum, o);
  float ls = v - mx - logf(ssum);
  if (l == 1) node_p[n] = expf(ls);
  int msk = mask[n];
  if (l == y[n] && msk) atomicAdd(&lossacc[0], ls);
  if (l == 0 && msk) atomicAdd(&lossacc[1], 1.f);
}

// ------- K11: SYMMETRIC Gram via f16-split MFMA (exact 4-term decomposition)
// xe = hi + lo (f16 each); xe_i.xe_j = hh + hl + lh + ll accumulated in f32
// by v_mfma_f32_16x16x32_f16 -> ~fp32 accuracy at matrix-pipe rate.
// Upper-triangle 128x128 blocks only; write tile + transpose.
// Fragments read directly from pre-swizzled global xh/xl (no LDS, no barriers).
// 4 waves per block in 2x2 (wr,wc); each wave: 64x64 out = 4x4 tiles of 16x16.
// C/D layout (verified): D[m][n]: n = lane&15, m = (lane>>4)*4 + reg.
__global__ __launch_bounds__(256, 2) void k_graph(
    const _Float16* __restrict__ xh, const _Float16* __restrict__ xl,
    const float* __restrict__ rinv, const float* __restrict__ node_p,
    float* __restrict__ gout, float* __restrict__ s1, float* __restrict__ s2) {
  int t = threadIdx.x;
  int lane = t & 63, w = t >> 6;
  int wr = w >> 1, wc = w & 1;
  int lhi = lane >> 4, llo = lane & 15;

  // ---- decode upper-triangle block pair (by <= bx) from linear block index
  int kb = blockIdx.x;
  int by = (int)(0.5f * (193.0f - sqrtf(37249.0f - 8.0f * (float)kb)));
  by = by < 0 ? 0 : (by > 95 ? 95 : by);
  while ((by + 1) * 96 - (((by + 1) * by) >> 1) <= kb) by++;
  while (by * 96 - ((by * (by - 1)) >> 1) > kb) by--;
  int bx = by + (kb - (by * 96 - ((by * (by - 1)) >> 1)));
  int I = by * 128, J = bx * 128;
  bool diag = (by == bx);

  // fragment base pointers (f16 units): panel*65536 + group*512 + lane*8
  const _Float16* pAh = xh + (size_t)by * 65536 + (size_t)(wr * 4) * 512 + lane * 8;
  const _Float16* pAl = xl + (size_t)by * 65536 + (size_t)(wr * 4) * 512 + lane * 8;
  const _Float16* pBh = xh + (size_t)bx * 65536 + (size_t)(wc * 4) * 512 + lane * 8;
  const _Float16* pBl = xl + (size_t)bx * 65536 + (size_t)(wc * 4) * 512 + lane * 8;

  f32x4 acc[4][4];
  #pragma unroll
  for (int r = 0; r < 4; ++r)
    #pragma unroll
    for (int c = 0; c < 4; ++c)
      acc[r][c] = (f32x4){0.f, 0.f, 0.f, 0.f};

  #pragma unroll 2
  for (int s = 0; s < 16; ++s) {
    f16x8 ah[4], al[4], bh[4], bl[4];
    #pragma unroll
    for (int r = 0; r < 4; ++r) {
      ah[r] = *(const f16x8*)(pAh + (size_t)s * 4096 + r * 512);
      al[r] = *(const f16x8*)(pAl + (size_t)s * 4096 + r * 512);
      bh[r] = *(const f16x8*)(pBh + (size_t)s * 4096 + r * 512);
      bl[r] = *(const f16x8*)(pBl + (size_t)s * 4096 + r * 512);
    }
    #pragma unroll
    for (int r = 0; r < 4; ++r)
      #pragma unroll
      for (int c = 0; c < 4; ++c) {
        acc[r][c] = __builtin_amdgcn_mfma_f32_16x16x32_f16(ah[r], bh[c], acc[r][c], 0, 0, 0);
        acc[r][c] = __builtin_amdgcn_mfma_f32_16x16x32_f16(ah[r], bl[c], acc[r][c], 0, 0, 0);
        acc[r][c] = __builtin_amdgcn_mfma_f32_16x16x32_f16(al[r], bh[c], acc[r][c], 0, 0, 0);
        acc[r][c] = __builtin_amdgcn_mfma_f32_16x16x32_f16(al[r], bl[c], acc[r][c], 0, 0, 0);
      }
  }

  // ---- normal side: graph[i][j] = dot * rinv[j]; store + row sums (s1/s2)
  float rj[4], pj[4];
  #pragma unroll
  for (int c = 0; c < 4; ++c) {
    int col = J + wc * 64 + c * 16 + llo;
    rj[c] = rinv[col]; pj[c] = node_p[col];
  }
  #pragma unroll
  for (int r = 0; r < 4; ++r) {
    #pragma unroll
    for (int q = 0; q < 4; ++q) {
      int row = I + wr * 64 + r * 16 + lhi * 4 + q;
      float* gp = gout + (size_t)row * N_NODES + J + wc * 64 + llo;
      float rs1 = 0.f, rs2 = 0.f;
      #pragma unroll
      for (int c = 0; c < 4; ++c) {
        float gv = acc[r][c][q] * rj[c];
        gp[c * 16] = gv;
        rs1 += gv; rs2 += gv * pj[c];
      }
      #pragma unroll
      for (int o = 1; o < 16; o <<= 1) { rs1 += __shfl_xor(rs1, o); rs2 += __shfl_xor(rs2, o); }
      if (llo == 0) { atomicAdd(&s1[row], rs1); atomicAdd(&s2[row], rs2); }
    }
  }

  // ---- transposed side (off-diagonal): graph[j][i] = dot * rinv[i]
  if (!diag) {
    float ri[4][4], pi[4][4];
    #pragma unroll
    for (int r = 0; r < 4; ++r)
      #pragma unroll
      for (int q = 0; q < 4; ++q) {
        int row = I + wr * 64 + r * 16 + lhi * 4 + q;
        ri[r][q] = rinv[row]; pi[r][q] = node_p[row];
      }
    #pragma unroll
    for (int c = 0; c < 4; ++c) {
      int col = J + wc * 64 + c * 16 + llo;       // output row
      float* gp = gout + (size_t)col * N_NODES + I + wr * 64;
      float cs1 = 0.f, cs2 = 0.f;
      #pragma unroll
      for (int r = 0; r < 4; ++r)
        #pragma unroll
        for (int q = 0; q < 4; ++q) {
          float gv = acc[r][c][q] * ri[r][q];
          gp[r * 16 + lhi * 4 + q] = gv;
          cs1 += gv; cs2 += gv * pi[r][q];
        }
      // reduce over lhi groups (lanes l, l^16, l^32, l^48)
      cs1 += __shfl_xor(cs1, 16); cs2 += __shfl_xor(cs2, 16);
      cs1 += __shfl_xor(cs1, 32); cs2 += __shfl_xor(cs2, 32);
      if (lhi == 0) { atomicAdd(&s1[col], cs1); atomicAdd(&s2[col], cs2); }
    }
  }
}

// ------------------------------------------------ K12: out1 softmax + loss
__global__ void k_final(const float* __restrict__ s1, const float* __restrict__ s2,
                        const float* __restrict__ lossacc, float* __restrict__ out) {
  int i = blockIdx.x * 256 + threadIdx.x;
  if (i < N_NODES) {
    float b = s2[i];          // adj_p
    float a = s1[i] - s2[i];  // adj_p_nag
    float m = fmaxf(a, b);
    float ea = expf(a - m), eb = expf(b - m);
    float inv = 1.f / (ea + eb);
    out[i * 2 + 0] = ea * inv;
    out[i * 2 + 1] = eb * inv;
  }
  if (i == 0) out[2 * N_NODES] = -lossacc[0] / lossacc[1];
}

// ============================================================= launch
extern "C" void kernel_launch(void* const* d_in, const int* in_sizes, int n_in,
                              void* d_out, int out_size, void* d_ws, size_t ws_size,
                              hipStream_t stream) {
  const float* x       = (const float*)d_in[0];
  const int*   ei      = (const int*)  d_in[1];
  const int*   y       = (const int*)  d_in[2];
  const int*   mask    = (const int*)  d_in[3];
  const float* W1      = (const float*)d_in[4];
  const float* a_src1  = (const float*)d_in[5];
  const float* a_dst1  = (const float*)d_in[6];
  const float* b1      = (const float*)d_in[7];
  const float* W2      = (const float*)d_in[8];
  const float* a_src2  = (const float*)d_in[9];
  const float* a_dst2  = (const float*)d_in[10];
  const float* b2      = (const float*)d_in[11];
  const float* gamma   = (const float*)d_in[12];
  const float* beta    = (const float*)d_in[13];
  const float* mean    = (const float*)d_in[14];
  const float* var     = (const float*)d_in[15];
  const float* emb_w   = (const float*)d_in[16];
  const float* logit_p = (const float*)d_in[17];

  float* out  = (float*)d_out;
  float* gout = out + 2 * N_NODES + 1;   // graph starts after out1 (N*2) + loss (1)

  char* w = (char*)d_ws;
  auto alloc = [&](size_t bytes) -> void* {
    void* p = (void*)w;
    w += (bytes + 255) & ~(size_t)255;
    return p;
  };
  float* xp1    = (float*)alloc((size_t)N_NODES * HID_CH * 4);
  float* hid    = (float*)alloc((size_t)N_NODES * HID_CH * 4);
  float* xp2    = (float*)alloc((size_t)N_NODES * OUT_CH * 4);
  float* as1    = (float*)alloc((size_t)N_NODES * 4);
  float* ad1    = (float*)alloc((size_t)N_NODES * 4);
  float* as2    = (float*)alloc((size_t)N_NODES * 4);
  float* ad2    = (float*)alloc((size_t)N_NODES * 4);
  float* rinv   = (float*)alloc((size_t)N_NODES * 4);
  float* node_p = (float*)alloc((size_t)N_NODES * 4);
  float* s1     = (float*)alloc((size_t)N_NODES * 4);
  float* s2     = (float*)alloc((size_t)N_NODES * 4);
  float* scale  = (float*)alloc((size_t)IN_CH * 4);
  float* lossacc= (float*)alloc(64);
  int*   deg    = (int*)  alloc((size_t)N_NODES * 4);
  int*   off    = (int*)  alloc((size_t)(N_NODES + 1) * 4);
  int*   cursor = (int*)  alloc((size_t)N_NODES * 4);
  int*   csr    = (int*)  alloc((size_t)TOT_EDGES * 4);
  _Float16* xh  = (_Float16*)alloc((size_t)N_NODES * IN_CH * 2);
  _Float16* xl  = (_Float16*)alloc((size_t)N_NODES * IN_CH * 2);

  k_init<<<N_NODES / 256, 256, 0, stream>>>(logit_p, emb_w, scale, s1, s2, lossacc, deg, cursor);
  k_rowsum<<<N_NODES / 4, 256, 0, stream>>>(x, scale, rinv);
  k_prep<<<(N_NODES * IN_CH / 8) / 256, 256, 0, stream>>>(x, scale, xh, xl);
  k_xp1<<<dim3(HID_CH / 128, N_NODES / 128), 256, 0, stream>>>(x, W1, xp1);
  k_alphas1<<<N_NODES / 4, 256, 0, stream>>>(xp1, a_src1, a_dst1, as1, ad1);
  k_degree<<<E_EDGES / 256, 256, 0, stream>>>(ei, deg);
  k_scan<<<1, 256, 0, stream>>>(deg, off);
  k_fill<<<(TOT_EDGES + 255) / 256, 256, 0, stream>>>(ei, off, cursor, csr);
  k_gat1<<<N_NODES, 256, 0, stream>>>(xp1, as1, ad1, off, csr, b1, gamma, beta, mean, var, hid);
  k_xp2<<<(N_NODES * OUT_CH) / 256, 256, 0, stream>>>(hid, W2, xp2);
  k_alphas2<<<N_NODES / 256, 256, 0, stream>>>(xp2, a_src2, a_dst2, as2, ad2);
  k_gat2<<<N_NODES, 64, 0, stream>>>(xp2, as2, ad2, off, csr, b2, y, mask, node_p, lossacc);
  // upper-triangle blocks only: 96*97/2 = 4656
  k_graph<<<4656, 256, 0, stream>>>(xh, xl, rinv, node_p, gout, s1, s2);
  k_final<<<N_NODES / 256, 256, 0, stream>>>(s1, s2, lossacc, out);
}

// Round 3
// 1315.421 us; speedup vs baseline: 1.5192x; 1.0184x over previous
//
#include <hip/hip_runtime.h>
#include <cstddef>
#include <cstdint>

#define N_NODES 12288
#define IN_CH   512
#define HID_CH  256
#define OUT_CH  8
#define E_EDGES 196608
#define TOT_EDGES (E_EDGES + N_NODES)

typedef _Float16 f16x8 __attribute__((ext_vector_type(8)));
typedef float    f32x4 __attribute__((ext_vector_type(4)));

// ---------------------------------------------------------------- K0: init
__global__ void k_init(const float* __restrict__ logit_p,
                       const float* __restrict__ emb_w,
                       float* __restrict__ scale,
                       float* __restrict__ s1, float* __restrict__ s2,
                       float* __restrict__ lossacc,
                       int* __restrict__ deg, int* __restrict__ cursor) {
  int i = blockIdx.x * 256 + threadIdx.x;
  if (i < IN_CH) {
    const float EPSf = 2.220446049250313e-16f;
    float p = 1.f / (1.f + expf(-logit_p[i]));
    // log(0.5+EPS)-log(0.5+EPS) cancels exactly
    float approx = logf(p + EPSf) - logf(1.f - p + EPSf);
    float keep = 1.f - 1.f / (1.f + expf(-approx / 0.1f));
    float ew = 1.f / (1.f + expf(-emb_w[i]));
    scale[i] = keep * ew;
  }
  if (i < N_NODES) { s1[i] = 0.f; s2[i] = 0.f; deg[i] = 1; cursor[i] = 0; }
  if (i < 4) lossacc[i] = 0.f;
}

// ------------------------------------------------- K1: rowsum -> 1/(rs+1e-6)
__global__ __launch_bounds__(256) void k_rowsum(const float* __restrict__ x,
                                                const float* __restrict__ scale,
                                                float* __restrict__ rinv) {
  int wave = threadIdx.x >> 6, lane = threadIdx.x & 63;
  int node = blockIdx.x * 4 + wave;
  const float* xr = x + (size_t)node * IN_CH;
  float s = 0.f;
  for (int k = lane; k < IN_CH; k += 64) s += xr[k] * scale[k];
  #pragma unroll
  for (int off = 32; off > 0; off >>= 1) s += __shfl_down(s, off);
  if (lane == 0) rinv[node] = 1.f / (s + 1e-6f);
}

// ---------------- K1b: prep xe = x*scale as f16 hi/lo planes, PRE-SWIZZLED
// into MFMA 16x16x32 fragment order. Storage (f16 units):
//   addr = p*65536 + s*4096 + g*512 + kb*128 + rowin*8 + kin
// where row = p*128 + g*16 + rowin, k = s*32 + kb*8 + kin.
// A fragment read for (panel p, kstep s, group g) is then: lane L reads
// 8 halves at addr = base + L*8  (contiguous, coalesced, 16B aligned).
__global__ __launch_bounds__(256) void k_prep(const float* __restrict__ x,
                                              const float* __restrict__ scale,
                                              _Float16* __restrict__ xh,
                                              _Float16* __restrict__ xl) {
  int tid = blockIdx.x * 256 + threadIdx.x;   // 786432 total
  int rowin = tid & 15;
  int kb    = (tid >> 4) & 3;
  int g     = (tid >> 6) & 7;
  int s     = (tid >> 9) & 15;
  int p     = tid >> 13;
  int row = p * 128 + g * 16 + rowin;
  int k   = s * 32 + kb * 8;
  const float* xp = x + (size_t)row * IN_CH + k;
  f16x8 h, l;
  #pragma unroll
  for (int j = 0; j < 8; ++j) {
    float v = xp[j] * scale[k + j];
    _Float16 hv = (_Float16)v;            // RTN
    h[j] = hv;
    l[j] = (_Float16)(v - (float)hv);     // residual, ~2^-22 rel error total
  }
  *(f16x8*)(xh + (size_t)tid * 8) = h;
  *(f16x8*)(xl + (size_t)tid * 8) = l;
}

// ---------------------------------------------------- K2: xp1 = x @ W1 (raw x)
__global__ __launch_bounds__(256) void k_xp1(const float* __restrict__ x,
                                             const float* __restrict__ W1,
                                             float* __restrict__ xp1) {
  __shared__ float As[16][132];
  __shared__ float Bs[16][132];
  int t = threadIdx.x;
  int I = blockIdx.y * 128, J = blockIdx.x * 128;
  int tx = t & 15, ty = t >> 4;
  int i0 = ty * 8, j0 = tx * 8;
  int q = t & 3, rr = t >> 2;
  int bk = t >> 4, bc = t & 15;
  float acc[8][8] = {};
  for (int k0 = 0; k0 < IN_CH; k0 += 16) {
    int kq = k0 + 4 * q;
    float4 a0 = *(const float4*)&x[(size_t)(I + rr)      * IN_CH + kq];
    float4 a1 = *(const float4*)&x[(size_t)(I + rr + 64) * IN_CH + kq];
    float4 w0 = *(const float4*)&W1[(size_t)(k0 + bk) * HID_CH + J + 4 * bc];
    float4 w1 = *(const float4*)&W1[(size_t)(k0 + bk) * HID_CH + J + 64 + 4 * bc];
    __syncthreads();
    As[4*q+0][rr]    = a0.x; As[4*q+1][rr]    = a0.y;
    As[4*q+2][rr]    = a0.z; As[4*q+3][rr]    = a0.w;
    As[4*q+0][rr+64] = a1.x; As[4*q+1][rr+64] = a1.y;
    As[4*q+2][rr+64] = a1.z; As[4*q+3][rr+64] = a1.w;
    *(float4*)&Bs[bk][4*bc]      = w0;
    *(float4*)&Bs[bk][64+4*bc]   = w1;
    __syncthreads();
    #pragma unroll
    for (int kk = 0; kk < 16; kk++) {
      float4 av0 = *(const float4*)&As[kk][i0];
      float4 av1 = *(const float4*)&As[kk][i0+4];
      float4 bv0 = *(const float4*)&Bs[kk][j0];
      float4 bv1 = *(const float4*)&Bs[kk][j0+4];
      float av[8] = {av0.x,av0.y,av0.z,av0.w,av1.x,av1.y,av1.z,av1.w};
      float bv[8] = {bv0.x,bv0.y,bv0.z,bv0.w,bv1.x,bv1.y,bv1.z,bv1.w};
      #pragma unroll
      for (int r = 0; r < 8; r++)
        #pragma unroll
        for (int c = 0; c < 8; c++)
          acc[r][c] = fmaf(av[r], bv[c], acc[r][c]);
    }
  }
  #pragma unroll
  for (int r = 0; r < 8; r++) {
    float* op = xp1 + (size_t)(I + i0 + r) * HID_CH + J + j0;
    #pragma unroll
    for (int c = 0; c < 8; c++) op[c] = acc[r][c];
  }
}

// ------------------------------------------- K3: alpha_s1/alpha_d1 per node
__global__ __launch_bounds__(256) void k_alphas1(const float* __restrict__ xp1,
                                                 const float* __restrict__ a_src,
                                                 const float* __restrict__ a_dst,
                                                 float* __restrict__ as1,
                                                 float* __restrict__ ad1) {
  int wave = threadIdx.x >> 6, lane = threadIdx.x & 63;
  int node = blockIdx.x * 4 + wave;
  const float* r = xp1 + (size_t)node * HID_CH;
  float s = 0.f, d = 0.f;
  for (int k = lane; k < HID_CH; k += 64) { float v = r[k]; s += v * a_src[k]; d += v * a_dst[k]; }
  #pragma unroll
  for (int off = 32; off > 0; off >>= 1) { s += __shfl_down(s, off); d += __shfl_down(d, off); }
  if (lane == 0) { as1[node] = s; ad1[node] = d; }
}

// ---------------------------------------------------------- K4: degree count
__global__ void k_degree(const int* __restrict__ ei, int* __restrict__ deg) {
  int e = blockIdx.x * 256 + threadIdx.x;
  if (e < E_EDGES) atomicAdd(&deg[ei[E_EDGES + e]], 1);
}

// ----------------------------------------------------- K5: offsets (scan)
__global__ void k_scan(const int* __restrict__ deg, int* __restrict__ off) {
  __shared__ int buf[256];
  __shared__ int base_s;
  int t = threadIdx.x;
  if (t == 0) { base_s = 0; off[0] = 0; }
  __syncthreads();
  for (int c0 = 0; c0 < N_NODES; c0 += 256) {
    buf[t] = deg[c0 + t];
    __syncthreads();
    for (int s = 1; s < 256; s <<= 1) {
      int tv = (t >= s) ? buf[t - s] : 0;
      __syncthreads();
      buf[t] += tv;
      __syncthreads();
    }
    off[c0 + t + 1] = base_s + buf[t];
    __syncthreads();
    if (t == 0) base_s += buf[255];
    __syncthreads();
  }
}

// ----------------------------------------------------------- K6: CSR fill
__global__ void k_fill(const int* __restrict__ ei, const int* __restrict__ off,
                       int* __restrict__ cursor, int* __restrict__ csr) {
  int e = blockIdx.x * 256 + threadIdx.x;
  if (e < E_EDGES) {
    int s = ei[e], d = ei[E_EDGES + e];
    int pos = atomicAdd(&cursor[d], 1);
    csr[off[d] + pos] = s;
  } else if (e < TOT_EDGES) {
    int n2 = e - E_EDGES;
    int pos = atomicAdd(&cursor[n2], 1);
    csr[off[n2] + pos] = n2;
  }
}

// ----------------------- K7: GAT1 aggregation + bias + BN(eval) + leaky(0.01)
__global__ __launch_bounds__(256) void k_gat1(
    const float* __restrict__ xp1, const float* __restrict__ as1,
    const float* __restrict__ ad1, const int* __restrict__ off,
    const int* __restrict__ csr, const float* __restrict__ b1,
    const float* __restrict__ gamma, const float* __restrict__ beta,
    const float* __restrict__ mean, const float* __restrict__ var,
    float* __restrict__ hid) {
  __shared__ float w_s[256];
  __shared__ int   src_s[256];
  __shared__ float red[256];
  int n = blockIdx.x, t = threadIdx.x;
  int beg = off[n], deg = off[n + 1] - beg;
  float adn = ad1[n];
  float m = -1e30f;
  for (int k = t; k < deg; k += 256) {
    float e = as1[csr[beg + k]] + adn;
    e = e > 0.f ? e : 0.2f * e;
    m = fmaxf(m, e);
  }
  red[t] = m; __syncthreads();
  for (int s = 128; s > 0; s >>= 1) { if (t < s) red[t] = fmaxf(red[t], red[t + s]); __syncthreads(); }
  m = red[0];
  __syncthreads();
  float acc = 0.f, dsum = 0.f;
  for (int k0 = 0; k0 < deg; k0 += 256) {
    int kk = k0 + t;
    float w = 0.f; int s = 0;
    if (kk < deg) {
      s = csr[beg + kk];
      float e = as1[s] + adn;
      e = e > 0.f ? e : 0.2f * e;
      w = expf(e - m);
    }
    w_s[t] = w; src_s[t] = s;
    dsum += w;
    __syncthreads();
    int lim = min(256, deg - k0);
    for (int q = 0; q < lim; q++)
      acc = fmaf(w_s[q], xp1[(size_t)src_s[q] * HID_CH + t], acc);
    __syncthreads();
  }
  red[t] = dsum; __syncthreads();
  for (int s = 128; s > 0; s >>= 1) { if (t < s) red[t] += red[t + s]; __syncthreads(); }
  float denom = red[0];
  float v = acc / (denom + 1e-16f) + b1[t];
  v = (v - mean[t]) * rsqrtf(var[t] + 1e-5f) * gamma[t] + beta[t];
  v = v > 0.f ? v : 0.01f * v;
  hid[(size_t)n * HID_CH + t] = v;
}

// --------------------------------------------------- K8: xp2 = hid @ W2
__global__ void k_xp2(const float* __restrict__ hid, const float* __restrict__ W2,
                      float* __restrict__ xp2) {
  int idx = blockIdx.x * 256 + threadIdx.x;
  if (idx >= N_NODES * OUT_CH) return;
  int i = idx >> 3, c = idx & 7;
  const float* h = hid + (size_t)i * HID_CH;
  float s = 0.f;
  #pragma unroll 8
  for (int k = 0; k < HID_CH; k++) s = fmaf(h[k], W2[k * OUT_CH + c], s);
  xp2[idx] = s;
}

// ------------------------------------------- K9: alpha_s2/alpha_d2 per node
__global__ void k_alphas2(const float* __restrict__ xp2,
                          const float* __restrict__ a_src2,
                          const float* __restrict__ a_dst2,
                          float* __restrict__ as2, float* __restrict__ ad2) {
  int i = blockIdx.x * 256 + threadIdx.x;
  if (i >= N_NODES) return;
  const float* r = xp2 + (size_t)i * OUT_CH;
  float s = 0.f, d = 0.f;
  #pragma unroll
  for (int c = 0; c < OUT_CH; c++) { float v = r[c]; s += v * a_src2[c]; d += v * a_dst2[c]; }
  as2[i] = s; ad2[i] = d;
}

// --------------- K10: GAT2 aggregation + log_softmax + node_p + loss pieces
__global__ __launch_bounds__(64) void k_gat2(
    const float* __restrict__ xp2, const float* __restrict__ as2,
    const float* __restrict__ ad2, const int* __restrict__ off,
    const int* __restrict__ csr, const float* __restrict__ b2,
    const int* __restrict__ y, const int* __restrict__ mask,
    float* __restrict__ node_p, float* __restrict__ lossacc) {
  int n = blockIdx.x, l = threadIdx.x;
  int beg = off[n], deg = off[n + 1] - beg;
  float adn = ad2[n];
  float m = -1e30f;
  for (int k = l; k < deg; k += 64) {
    float e = as2[csr[beg + k]] + adn;
    e = e > 0.f ? e : 0.2f * e;
    m = fmaxf(m, e);
  }
  #pragma unroll
  for (int o = 32; o > 0; o >>= 1) m = fmaxf(m, __shfl_xor(m, o));
  int g = l >> 3, c = l & 7;
  float acc = 0.f, dsum = 0.f;
  for (int k0 = 0; k0 < deg; k0 += 8) {
    int kk = k0 + g;
    if (kk < deg) {
      int s = csr[beg + kk];
      float e = as2[s] + adn;
      e = e > 0.f ? e : 0.2f * e;
      float w = expf(e - m);
      acc = fmaf(w, xp2[(size_t)s * OUT_CH + c], acc);
      if (c == 0) dsum += w;
    }
  }
  #pragma unroll
  for (int o = 8; o < 64; o <<= 1) { acc += __shfl_xor(acc, o); dsum += __shfl_xor(dsum, o); }
  float denom = __shfl(dsum, 0);
  float v = acc / (denom + 1e-16f) + b2[c];
  float mx = v;
  #pragma unroll
  for (int o = 1; o < 8; o <<= 1) mx = fmaxf(mx, __shfl_xor(mx, o));
  float ex = expf(v - mx), ssum = ex;
  #pragma unroll
  for (int o = 1; o < 8; o <<= 1) ssum += __shfl_xor(ssum, o);
  float ls = v - mx - logf(ssum);
  if (l == 1) node_p[n] = expf(ls);
  int msk = mask[n];
  if (l == y[n] && msk) atomicAdd(&lossacc[0], ls);
  if (l == 0 && msk) atomicAdd(&lossacc[1], 1.f);
}

// ------- K11: SYMMETRIC Gram via f16-split MFMA (3-term: hh + hl + lh; the
// ll term is ~2^-22 relative — below fp32 rounding — and dropped).
// Upper-triangle 128x128 blocks; write tile + transpose.
// All gout stores NONTEMPORAL (gout is never re-read on device) to avoid
// L2 write-allocate RMW fetches (~604 MB of spurious FETCH_SIZE measured).
// Transposed side staged through LDS so stores are 256B contiguous per wave.
// 4 waves per block in 2x2 (wr,wc); each wave: 64x64 out = 4x4 tiles of 16x16.
// C/D layout: D[m][n]: n = lane&15, m = (lane>>4)*4 + reg.
__global__ __launch_bounds__(256, 2) void k_graph(
    const _Float16* __restrict__ xh, const _Float16* __restrict__ xl,
    const float* __restrict__ rinv, const float* __restrict__ node_p,
    float* __restrict__ gout, float* __restrict__ s1, float* __restrict__ s2) {
  __shared__ float tbuf[4][16][67];
  int t = threadIdx.x;
  int lane = t & 63, w = t >> 6;
  int wr = w >> 1, wc = w & 1;
  int lhi = lane >> 4, llo = lane & 15;

  // ---- decode upper-triangle block pair (by <= bx) from linear block index
  int kb = blockIdx.x;
  int by = (int)(0.5f * (193.0f - sqrtf(37249.0f - 8.0f * (float)kb)));
  by = by < 0 ? 0 : (by > 95 ? 95 : by);
  while ((by + 1) * 96 - (((by + 1) * by) >> 1) <= kb) by++;
  while (by * 96 - ((by * (by - 1)) >> 1) > kb) by--;
  int bx = by + (kb - (by * 96 - ((by * (by - 1)) >> 1)));
  int I = by * 128, J = bx * 128;
  bool diag = (by == bx);

  // fragment base pointers (f16 units): panel*65536 + group*512 + lane*8
  const _Float16* pAh = xh + (size_t)by * 65536 + (size_t)(wr * 4) * 512 + lane * 8;
  const _Float16* pAl = xl + (size_t)by * 65536 + (size_t)(wr * 4) * 512 + lane * 8;
  const _Float16* pBh = xh + (size_t)bx * 65536 + (size_t)(wc * 4) * 512 + lane * 8;
  const _Float16* pBl = xl + (size_t)bx * 65536 + (size_t)(wc * 4) * 512 + lane * 8;

  f32x4 acc[4][4];
  #pragma unroll
  for (int r = 0; r < 4; ++r)
    #pragma unroll
    for (int c = 0; c < 4; ++c)
      acc[r][c] = (f32x4){0.f, 0.f, 0.f, 0.f};

  #pragma unroll 2
  for (int s = 0; s < 16; ++s) {
    f16x8 ah[4], al[4], bh[4], bl[4];
    #pragma unroll
    for (int r = 0; r < 4; ++r) {
      ah[r] = *(const f16x8*)(pAh + (size_t)s * 4096 + r * 512);
      al[r] = *(const f16x8*)(pAl + (size_t)s * 4096 + r * 512);
      bh[r] = *(const f16x8*)(pBh + (size_t)s * 4096 + r * 512);
      bl[r] = *(const f16x8*)(pBl + (size_t)s * 4096 + r * 512);
    }
    #pragma unroll
    for (int r = 0; r < 4; ++r)
      #pragma unroll
      for (int c = 0; c < 4; ++c) {
        acc[r][c] = __builtin_amdgcn_mfma_f32_16x16x32_f16(ah[r], bh[c], acc[r][c], 0, 0, 0);
        acc[r][c] = __builtin_amdgcn_mfma_f32_16x16x32_f16(ah[r], bl[c], acc[r][c], 0, 0, 0);
        acc[r][c] = __builtin_amdgcn_mfma_f32_16x16x32_f16(al[r], bh[c], acc[r][c], 0, 0, 0);
      }
  }

  // ---- normal side: graph[i][j] = dot * rinv[j]; nt stores + row sums
  float rj[4], pj[4];
  #pragma unroll
  for (int c = 0; c < 4; ++c) {
    int col = J + wc * 64 + c * 16 + llo;
    rj[c] = rinv[col]; pj[c] = node_p[col];
  }
  #pragma unroll
  for (int r = 0; r < 4; ++r) {
    #pragma unroll
    for (int q = 0; q < 4; ++q) {
      int row = I + wr * 64 + r * 16 + lhi * 4 + q;
      float* gp = gout + (size_t)row * N_NODES + J + wc * 64 + llo;
      float rs1 = 0.f, rs2 = 0.f;
      #pragma unroll
      for (int c = 0; c < 4; ++c) {
        float gv = acc[r][c][q] * rj[c];
        __builtin_nontemporal_store(gv, gp + c * 16);
        rs1 += gv; rs2 += gv * pj[c];
      }
      #pragma unroll
      for (int o = 1; o < 16; o <<= 1) { rs1 += __shfl_xor(rs1, o); rs2 += __shfl_xor(rs2, o); }
      if (llo == 0) { atomicAdd(&s1[row], rs1); atomicAdd(&s2[row], rs2); }
    }
  }

  // ---- transposed side (off-diagonal): graph[j][i] = dot * rinv[i]
  // Staged through LDS per 16-row chunk so each wave store is 256B contiguous.
  if (!diag) {
    float ri[4][4], pi[4][4];
    #pragma unroll
    for (int r = 0; r < 4; ++r)
      #pragma unroll
      for (int q = 0; q < 4; ++q) {
        int row = I + wr * 64 + r * 16 + lhi * 4 + q;
        ri[r][q] = rinv[row]; pi[r][q] = node_p[row];
      }
    for (int c = 0; c < 4; ++c) {
      int col = J + wc * 64 + c * 16 + llo;       // output row for this lane
      float cs1 = 0.f, cs2 = 0.f;
      #pragma unroll
      for (int r = 0; r < 4; ++r)
        #pragma unroll
        for (int q = 0; q < 4; ++q) {
          float gv = acc[r][c][q] * ri[r][q];
          tbuf[w][llo][r * 16 + lhi * 4 + q] = gv;
          cs1 += gv; cs2 += gv * pi[r][q];
        }
      // reduce over lhi groups (lanes l, l^16, l^32, l^48)
      cs1 += __shfl_xor(cs1, 16); cs2 += __shfl_xor(cs2, 16);
      cs1 += __shfl_xor(cs1, 32); cs2 += __shfl_xor(cs2, 32);
      if (lhi == 0) { atomicAdd(&s1[col], cs1); atomicAdd(&s2[col], cs2); }
      __syncthreads();
      // coalesced nt store: 16 rows x 64 consecutive floats each
      #pragma unroll
      for (int w2 = 0; w2 < 16; ++w2) {
        int orow = J + wc * 64 + c * 16 + w2;
        __builtin_nontemporal_store(tbuf[w][w2][lane],
            gout + (size_t)orow * N_NODES + I + wr * 64 + lane);
      }
      __syncthreads();
    }
  }
}

// ------------------------------------------------ K12: out1 softmax + loss
__global__ void k_final(const float* __restrict__ s1, const float* __restrict__ s2,
                        const float* __restrict__ lossacc, float* __restrict__ out) {
  int i = blockIdx.x * 256 + threadIdx.x;
  if (i < N_NODES) {
    float b = s2[i];          // adj_p
    float a = s1[i] - s2[i];  // adj_p_nag
    float m = fmaxf(a, b);
    float ea = expf(a - m), eb = expf(b - m);
    float inv = 1.f / (ea + eb);
    out[i * 2 + 0] = ea * inv;
    out[i * 2 + 1] = eb * inv;
  }
  if (i == 0) out[2 * N_NODES] = -lossacc[0] / lossacc[1];
}

// ============================================================= launch
extern "C" void kernel_launch(void* const* d_in, const int* in_sizes, int n_in,
                              void* d_out, int out_size, void* d_ws, size_t ws_size,
                              hipStream_t stream) {
  const float* x       = (const float*)d_in[0];
  const int*   ei      = (const int*)  d_in[1];
  const int*   y       = (const int*)  d_in[2];
  const int*   mask    = (const int*)  d_in[3];
  const float* W1      = (const float*)d_in[4];
  const float* a_src1  = (const float*)d_in[5];
  const float* a_dst1  = (const float*)d_in[6];
  const float* b1      = (const float*)d_in[7];
  const float* W2      = (const float*)d_in[8];
  const float* a_src2  = (const float*)d_in[9];
  const float* a_dst2  = (const float*)d_in[10];
  const float* b2      = (const float*)d_in[11];
  const float* gamma   = (const float*)d_in[12];
  const float* beta    = (const float*)d_in[13];
  const float* mean    = (const float*)d_in[14];
  const float* var     = (const float*)d_in[15];
  const float* emb_w   = (const float*)d_in[16];
  const float* logit_p = (const float*)d_in[17];

  float* out  = (float*)d_out;
  float* gout = out + 2 * N_NODES + 1;   // graph starts after out1 (N*2) + loss (1)

  char* w = (char*)d_ws;
  auto alloc = [&](size_t bytes) -> void* {
    void* p = (void*)w;
    w += (bytes + 255) & ~(size_t)255;
    return p;
  };
  float* xp1    = (float*)alloc((size_t)N_NODES * HID_CH * 4);
  float* hid    = (float*)alloc((size_t)N_NODES * HID_CH * 4);
  float* xp2    = (float*)alloc((size_t)N_NODES * OUT_CH * 4);
  float* as1    = (float*)alloc((size_t)N_NODES * 4);
  float* ad1    = (float*)alloc((size_t)N_NODES * 4);
  float* as2    = (float*)alloc((size_t)N_NODES * 4);
  float* ad2    = (float*)alloc((size_t)N_NODES * 4);
  float* rinv   = (float*)alloc((size_t)N_NODES * 4);
  float* node_p = (float*)alloc((size_t)N_NODES * 4);
  float* s1     = (float*)alloc((size_t)N_NODES * 4);
  float* s2     = (float*)alloc((size_t)N_NODES * 4);
  float* scale  = (float*)alloc((size_t)IN_CH * 4);
  float* lossacc= (float*)alloc(64);
  int*   deg    = (int*)  alloc((size_t)N_NODES * 4);
  int*   off    = (int*)  alloc((size_t)(N_NODES + 1) * 4);
  int*   cursor = (int*)  alloc((size_t)N_NODES * 4);
  int*   csr    = (int*)  alloc((size_t)TOT_EDGES * 4);
  _Float16* xh  = (_Float16*)alloc((size_t)N_NODES * IN_CH * 2);
  _Float16* xl  = (_Float16*)alloc((size_t)N_NODES * IN_CH * 2);

  k_init<<<N_NODES / 256, 256, 0, stream>>>(logit_p, emb_w, scale, s1, s2, lossacc, deg, cursor);
  k_rowsum<<<N_NODES / 4, 256, 0, stream>>>(x, scale, rinv);
  k_prep<<<(N_NODES * IN_CH / 8) / 256, 256, 0, stream>>>(x, scale, xh, xl);
  k_xp1<<<dim3(HID_CH / 128, N_NODES / 128), 256, 0, stream>>>(x, W1, xp1);
  k_alphas1<<<N_NODES / 4, 256, 0, stream>>>(xp1, a_src1, a_dst1, as1, ad1);
  k_degree<<<E_EDGES / 256, 256, 0, stream>>>(ei, deg);
  k_scan<<<1, 256, 0, stream>>>(deg, off);
  k_fill<<<(TOT_EDGES + 255) / 256, 256, 0, stream>>>(ei, off, cursor, csr);
  k_gat1<<<N_NODES, 256, 0, stream>>>(xp1, as1, ad1, off, csr, b1, gamma, beta, mean, var, hid);
  k_xp2<<<(N_NODES * OUT_CH) / 256, 256, 0, stream>>>(hid, W2, xp2);
  k_alphas2<<<N_NODES / 256, 256, 0, stream>>>(xp2, a_src2, a_dst2, as2, ad2);
  k_gat2<<<N_NODES, 64, 0, stream>>>(xp2, as2, ad2, off, csr, b2, y, mask, node_p, lossacc);
  // upper-triangle blocks only: 96*97/2 = 4656
  k_graph<<<4656, 256, 0, stream>>>(xh, xl, rinv, node_p, gout, s1, s2);
  k_final<<<N_NODES / 256, 256, 0, stream>>>(s1, s2, lossacc, out);
}